// Round 3
// baseline (104.452 us; speedup 1.0000x reference)
//
#include <hip/hip_runtime.h>

#define NCLS 345
#define CPAD 384
#define DIM  512
#define MAXS 512
#define BCAP 256
#define BM   64
#define BK   64

typedef float f32x4 __attribute__((ext_vector_type(4)));
typedef float f32x4u __attribute__((ext_vector_type(4), aligned(4)));
typedef short s16x8 __attribute__((ext_vector_type(8)));
typedef unsigned long long u64;

__device__ __forceinline__ short f2bf(float f) {
  union { float f; unsigned u; } v; v.f = f;
  unsigned r = v.u + 0x7fffu + ((v.u >> 16) & 1u);   // round-to-nearest-even
  return (short)(r >> 16);
}

// ---- Stage 1: one pass over N, bucket (ent_bits<<32)|idx per class ----
// ent in [0,1): positive-float bits are order-monotone, so u64 compare
// reproduces the stable (ent, idx) argsort order exactly.
__global__ __launch_bounds__(256) void scan_classes(
    const float* __restrict__ ent, const int* __restrict__ y_hat,
    u64* __restrict__ bucket, int* __restrict__ cnt, int N)
{
  int i = blockIdx.x * 256 + threadIdx.x;
  if (i >= N) return;
  int c = y_hat[i];
  unsigned eb = __float_as_uint(ent[i]);
  u64 key = ((u64)eb << 32) | (unsigned)i;
  int p = atomicAdd(&cnt[c], 1);
  if (p < BCAP) bucket[(size_t)c * BCAP + p] = key;
}

// ---- Stage 2: per-class select (exact stable rank) + normalized-row sum ----
__global__ __launch_bounds__(512) void select_accum(
    const float* __restrict__ supports, const u64* __restrict__ bucket,
    const int* __restrict__ cnt, const int* __restrict__ fKp,
    short* __restrict__ Wt)
{
  const int c = blockIdx.x;
  const int tid = threadIdx.x;
  const int lane = tid & 63, w = tid >> 6;
  __shared__ u64   s_key[BCAP];
  __shared__ int   s_selidx[BCAP];
  __shared__ int   s_nsel;
  __shared__ float s_part[8][DIM];   // 16 KB
  __shared__ float s_red[8];
  if (tid == 0) s_nsel = 0;
  const int S = (c < NCLS) ? min(cnt[c], BCAP) : 0;
  const int K = fKp[0];
  for (int e = tid; e < S; e += 512) s_key[e] = bucket[(size_t)c * BCAP + e];
  __syncthreads();
  for (int e = tid; e < S; e += 512) {
    u64 ke = s_key[e];
    int r = 0;
    for (int j = 0; j < S; ++j) r += (s_key[j] < ke) ? 1 : 0;
    if (r < K) { int p = atomicAdd(&s_nsel, 1); s_selidx[p] = (int)(unsigned)(ke & 0xffffffffull); }
  }
  __syncthreads();
  const int nsel = s_nsel;
  // 8 waves; 2 rows in flight per wave to overlap the shuffle chains
  f32x4 p0 = {0.f,0.f,0.f,0.f}, p1 = {0.f,0.f,0.f,0.f};
  for (int e0 = w; e0 < nsel; e0 += 16) {
    const int e1 = e0 + 8;
    const bool h1 = (e1 < nsel);                 // wave-uniform
    const f32x4* r0 = (const f32x4*)(supports + (size_t)s_selidx[e0] * DIM);
    f32x4 a0 = r0[lane], a1 = r0[lane + 64];
    f32x4 b0 = {0.f,0.f,0.f,0.f}, b1 = {0.f,0.f,0.f,0.f};
    if (h1) {
      const f32x4* r1 = (const f32x4*)(supports + (size_t)s_selidx[e1] * DIM);
      b0 = r1[lane]; b1 = r1[lane + 64];
    }
    float s0 = 0.f, s1 = 0.f;
#pragma unroll
    for (int j = 0; j < 4; ++j) {
      s0 = fmaf(a0[j], a0[j], s0); s0 = fmaf(a1[j], a1[j], s0);
      s1 = fmaf(b0[j], b0[j], s1); s1 = fmaf(b1[j], b1[j], s1);
    }
#pragma unroll
    for (int off = 32; off; off >>= 1) { s0 += __shfl_xor(s0, off); s1 += __shfl_xor(s1, off); }
    float c0 = 1.f / fmaxf(sqrtf(s0), 1e-12f);
    float c1 = 1.f / fmaxf(sqrtf(s1), 1e-12f);
#pragma unroll
    for (int j = 0; j < 4; ++j) { p0[j] = fmaf(a0[j], c0, p0[j]); p1[j] = fmaf(a1[j], c0, p1[j]); }
    if (h1) {
#pragma unroll
      for (int j = 0; j < 4; ++j) { p0[j] = fmaf(b0[j], c1, p0[j]); p1[j] = fmaf(b1[j], c1, p1[j]); }
    }
  }
  *(f32x4*)&s_part[w][lane * 4]       = p0;
  *(f32x4*)&s_part[w][256 + lane * 4] = p1;
  __syncthreads();
  float acc = 0.f;
#pragma unroll
  for (int ww = 0; ww < 8; ++ww) acc += s_part[ww][tid];
  float sq = acc * acc;
#pragma unroll
  for (int off = 32; off; off >>= 1) sq += __shfl_xor(sq, off);
  if (lane == 0) s_red[w] = sq;
  __syncthreads();
  float tot = 0.f;
#pragma unroll
  for (int ww = 0; ww < 8; ++ww) tot += s_red[ww];
  float sc = 1.f / fmaxf(sqrtf(tot), 1e-12f);
  Wt[(size_t)c * DIM + tid] = f2bf(acc * sc);
}

// ---- Kernel B: out[M,345] = z[M,512] @ W  via bf16 MFMA, B^T layout ----
// Pipelined: reg-prefetch B 1 tile ahead (L2), A 2 tiles ahead (HBM).
// Raw s_barrier (no vmcnt drain) keeps prefetches in flight across barriers.
// Swapped MFMA operands -> per-lane 4 consecutive C-cols -> f32x4 stores.
__global__ __launch_bounds__(512) void gemm_zw(
    const float* __restrict__ z, const short* __restrict__ Wt,
    float* __restrict__ out)
{
  __shared__ __align__(16) short lA[BM * BK];     // 8 KB
  __shared__ __align__(16) short lB[CPAD * BK];   // 48 KB
  const int tid = threadIdx.x;
  const int bm = blockIdx.x;
  const int rb  = tid >> 3;    // staging row 0..63
  const int seg = tid & 7;     // 16B segment within row
  const float* gA = z  + (size_t)(bm * BM + rb) * DIM + seg * 8;
  const short* gB = Wt + (size_t)rb * DIM + seg * 8;
  const unsigned wA = (unsigned)(rb * 128 + seg * 16) ^ ((rb & 7) << 4);
  char* const cA = (char*)lA;
  char* const cB = (char*)lB;

  const int lane = tid & 63, wid = tid >> 6;
  const int wm = wid >> 2, wn = wid & 3;
  const int fr = lane & 15, fq = lane >> 4;
  unsigned roA[2], roB[6];
#pragma unroll
  for (int mt = 0; mt < 2; ++mt) {
    int r = wm * 32 + mt * 16 + fr;
    roA[mt] = (unsigned)(r * 128 + fq * 16) ^ ((r & 7) << 4);
  }
#pragma unroll
  for (int nt = 0; nt < 6; ++nt) {
    int r = wn * 96 + nt * 16 + fr;
    roB[nt] = (unsigned)(r * 128 + fq * 16) ^ ((r & 7) << 4);
  }
  f32x4 acc[2][6];
#pragma unroll
  for (int mt = 0; mt < 2; ++mt)
#pragma unroll
    for (int nt = 0; nt < 6; ++nt) acc[mt][nt] = f32x4{0.f, 0.f, 0.f, 0.f};

  // prologue: B(0) first (older in vmem queue), then A(0), A(1)
  s16x8 rB[6];
  f32x4 rA0[2], rA1[2];
#pragma unroll
  for (int rep = 0; rep < 6; ++rep)
    rB[rep] = *(const s16x8*)(gB + (size_t)rep * 64 * DIM);
  rA0[0] = *(const f32x4*)gA;
  rA0[1] = *(const f32x4*)(gA + 4);
  rA1[0] = *(const f32x4*)(gA + BK);
  rA1[1] = *(const f32x4*)(gA + BK + 4);

#pragma unroll
  for (int kt = 0; kt < DIM / BK; ++kt) {
    s16x8 a16;
#pragma unroll
    for (int j = 0; j < 4; ++j) { a16[j] = f2bf(rA0[0][j]); a16[4 + j] = f2bf(rA0[1][j]); }
    __builtin_amdgcn_s_barrier();                 // all waves done reading prev tile
    *(s16x8*)(cA + wA) = a16;
#pragma unroll
    for (int rep = 0; rep < 6; ++rep)
      *(s16x8*)(cB + wA + rep * 8192) = rB[rep];  // waits vmcnt only for B(kt)
    asm volatile("s_waitcnt lgkmcnt(0)" ::: "memory");
    __builtin_amdgcn_sched_barrier(0);
    __builtin_amdgcn_s_barrier();                 // tile kt visible
    // prefetch: B(kt+1) first, then A(kt+2) (keeps B older in the queue)
    if (kt < 7) {
#pragma unroll
      for (int rep = 0; rep < 6; ++rep)
        rB[rep] = *(const s16x8*)(gB + (size_t)rep * 64 * DIM + (kt + 1) * BK);
    }
    rA0[0] = rA1[0]; rA0[1] = rA1[1];
    if (kt < 6) {
      rA1[0] = *(const f32x4*)(gA + (kt + 2) * BK);
      rA1[1] = *(const f32x4*)(gA + (kt + 2) * BK + 4);
    }
#pragma unroll
    for (int kk = 0; kk < 2; ++kk) {
      const unsigned kx = (unsigned)(kk << 6);
      s16x8 af[2], bfr[6];
#pragma unroll
      for (int mt = 0; mt < 2; ++mt) af[mt] = *(const s16x8*)(cA + (roA[mt] ^ kx));
#pragma unroll
      for (int nt = 0; nt < 6; ++nt) bfr[nt] = *(const s16x8*)(cB + (roB[nt] ^ kx));
#pragma unroll
      for (int mt = 0; mt < 2; ++mt)
#pragma unroll
        for (int nt = 0; nt < 6; ++nt)
          acc[mt][nt] = __builtin_amdgcn_mfma_f32_16x16x32_bf16(bfr[nt], af[mt], acc[mt][nt], 0, 0, 0);
    }
  }
  // epilogue (swapped-D layout): lane fr = C-row, (fq, reg j) = C-col
  const int rowb = bm * BM + wm * 32;
  const int colb = wn * 96 + fq * 4;
#pragma unroll
  for (int mt = 0; mt < 2; ++mt) {
    const int row = rowb + mt * 16 + fr;
    float* prow = out + (size_t)row * NCLS;
#pragma unroll
    for (int nt = 0; nt < 6; ++nt) {
      const int col = colb + nt * 16;
      if (col + 3 < NCLS) {
        *(f32x4u*)(prow + col) = acc[mt][nt];
      } else if (col < NCLS) {
#pragma unroll
        for (int j = 0; j < 4; ++j)
          if (col + j < NCLS) prow[col + j] = acc[mt][nt][j];
      }
    }
  }
}

extern "C" void kernel_launch(void* const* d_in, const int* in_sizes, int n_in,
                              void* d_out, int out_size, void* d_ws, size_t ws_size,
                              hipStream_t stream) {
  const float* z        = (const float*)d_in[0];
  const float* supports = (const float*)d_in[1];
  const float* ent      = (const float*)d_in[2];
  const int*   y_hat    = (const int*)d_in[3];
  const int*   fK       = (const int*)d_in[4];
  float* out = (float*)d_out;
  short* Wt  = (short*)d_ws;
  const int N = in_sizes[2];
  const int M = in_sizes[0] / DIM;

  const size_t offC = (size_t)CPAD * DIM * 2;          // 393216
  const size_t offB = offC + 2048;
  int* cnt    = (int*)((char*)d_ws + offC);
  u64* bucket = (u64*)((char*)d_ws + offB);
  hipMemsetAsync(cnt, 0, CPAD * sizeof(int), stream);
  scan_classes<<<dim3((N + 255) / 256), dim3(256), 0, stream>>>(ent, y_hat, bucket, cnt, N);
  select_accum<<<dim3(CPAD), dim3(512), 0, stream>>>(supports, bucket, cnt, fK, Wt);
  gemm_zw<<<dim3(M / BM), dim3(512), 0, stream>>>(z, Wt, out);
}